// Round 1
// baseline (7569.911 us; speedup 1.0000x reference)
//
#include <hip/hip_runtime.h>
#include <hip/hip_bf16.h>
#include <stdint.h>

#define B_    64
#define T_    1024
#define DIN   136
#define DINP  160
#define H_    256
#define G4H   1024

typedef __bf16 bf16;
typedef __bf16 bf16x8 __attribute__((ext_vector_type(8)));
typedef float  floatx4 __attribute__((ext_vector_type(4)));
typedef int    int4v  __attribute__((ext_vector_type(4)));

// ---------------- pack kernels ----------------
__global__ void k_pack_x(const float* __restrict__ x, bf16* __restrict__ xp) {
  const int n = T_ * B_ * DINP;
  for (int i = blockIdx.x * blockDim.x + threadIdx.x; i < n; i += gridDim.x * blockDim.x) {
    int k  = i % DINP;
    int tb = i / DINP;
    int b  = tb % B_;
    int t  = tb / B_;
    float v = 0.f;
    if (k < DIN) v = x[(b * T_ + t) * DIN + k];
    xp[i] = (bf16)v;   // layout [t][b][k], k zero-padded to 160
  }
}

// packed row r = 4*hid + gate  ->  orig row = gate*256 + hid
__global__ void k_pack_whh(const float* __restrict__ wf, const float* __restrict__ wb,
                           bf16* __restrict__ wp) {
  const int n = 2 * G4H * H_;
  for (int i = blockIdx.x * blockDim.x + threadIdx.x; i < n; i += gridDim.x * blockDim.x) {
    int k   = i & (H_ - 1);
    int r   = (i >> 8) & (G4H - 1);
    int dir = i >> 18;
    int orig = ((r & 3) << 8) | (r >> 2);
    const float* w = dir ? wb : wf;
    wp[i] = (bf16)w[orig * H_ + k];
  }
}

__global__ void k_pack_wih(const float* __restrict__ wf, const float* __restrict__ wb,
                           bf16* __restrict__ wp) {
  const int n = 2 * G4H * DINP;
  for (int i = blockIdx.x * blockDim.x + threadIdx.x; i < n; i += gridDim.x * blockDim.x) {
    int k   = i % DINP;
    int r   = (i / DINP) & (G4H - 1);
    int dir = i / (G4H * DINP);
    int orig = ((r & 3) << 8) | (r >> 2);
    const float* w = dir ? wb : wf;
    float v = (k < DIN) ? w[orig * DIN + k] : 0.f;
    wp[i] = (bf16)v;
  }
}

__global__ void k_pack_bias(const float* __restrict__ bihf, const float* __restrict__ bhhf,
                            const float* __restrict__ bihb, const float* __restrict__ bhhb,
                            float* __restrict__ bs) {
  int i = blockIdx.x * blockDim.x + threadIdx.x;
  if (i >= 2 * G4H) return;
  int r = i & (G4H - 1); int dir = i >> 10;
  int orig = ((r & 3) << 8) | (r >> 2);
  bs[i] = dir ? (bihb[orig] + bhhb[orig]) : (bihf[orig] + bhhf[orig]);
}

// ---------------- persistent grouped LSTM ----------------
// grid = 128 blocks: bx = gid*16 + s ; gid = dir*4 + btile (8 groups), s = hidden-slice 0..15
// block = 256 threads = 4 waves; wave wv owns 16 packed gate rows = 4 hidden units.
__global__ __launch_bounds__(256) void k_lstm(
    const bf16* __restrict__ xp, const bf16* __restrict__ whhp,
    const bf16* __restrict__ wihp, const float* __restrict__ bs,
    bf16* __restrict__ hseq, unsigned* __restrict__ cnt)
{
  __shared__ bf16 sm[31872];                 // 63744 B
  bf16* Whh_s = sm;                          // 64 x 264
  bf16* Wih_s = sm + 16896;                  // 64 x 168
  bf16* h_s   = sm + 27648;                  // 16 x 264
  unsigned short* h_su = (unsigned short*)h_s;

  const int tid = threadIdx.x;
  const int wv  = tid >> 6;
  const int l   = tid & 63;
  const int q   = l >> 4;
  const int m   = l & 15;

  const int bx    = blockIdx.x;
  const int gid   = bx >> 4;
  const int s     = bx & 15;
  const int dir   = gid >> 2;
  const int btile = gid & 3;

  // ---- stage weight slices into LDS (once) ----
  {
    const bf16* src = whhp + (size_t)(dir * G4H + s * 64) * H_;
    for (int ch = tid; ch < 2048; ch += 256) {
      int row = ch >> 5, c16 = ch & 31;
      *(int4v*)&Whh_s[row * 264 + c16 * 8] = *(const int4v*)&src[row * 256 + c16 * 8];
    }
    const bf16* src2 = wihp + (size_t)(dir * G4H + s * 64) * DINP;
    for (int ch = tid; ch < 1280; ch += 256) {
      int row = ch / 20, c16 = ch % 20;
      *(int4v*)&Wih_s[row * 168 + c16 * 8] = *(const int4v*)&src2[row * 160 + c16 * 8];
    }
  }
  const int rbase = dir * G4H + s * 64 + wv * 16 + q * 4;
  const float b0 = bs[rbase + 0], b1 = bs[rbase + 1], b2 = bs[rbase + 2], b3 = bs[rbase + 3];

  __syncthreads();

  const int hid   = s * 16 + wv * 4 + q;     // 0..255
  const int bglob = btile * 16 + m;          // 0..63
  unsigned* const mycnt = cnt + gid * T_;

  float c = 0.f;
  bf16x8 xf[5];
  {
    const int xt0 = dir ? (T_ - 1) : 0;
    const bf16* xr = xp + (size_t)(xt0 * B_ + bglob) * DINP + q * 8;
#pragma unroll
    for (int kk = 0; kk < 5; ++kk) xf[kk] = *(const bf16x8*)&xr[kk * 32];
  }

  for (int t = 0; t < T_; ++t) {
    const int xt = dir ? (T_ - 1 - t) : t;
    floatx4 acc = {b0, b1, b2, b3};

    // input-projection MFMAs (independent of h)
    {
      const bf16* Ar = &Wih_s[(wv * 16 + m) * 168 + q * 8];
#pragma unroll
      for (int kk = 0; kk < 5; ++kk)
        acc = __builtin_amdgcn_mfma_f32_16x16x32_bf16(*(const bf16x8*)&Ar[kk * 32], xf[kk], acc, 0, 0, 0);
    }
    // prefetch next step's x fragments (hidden under the poll)
    if (t + 1 < T_) {
      const int xtn = dir ? (T_ - 2 - t) : (t + 1);
      const bf16* xr = xp + (size_t)(xtn * B_ + bglob) * DINP + q * 8;
#pragma unroll
      for (int kk = 0; kk < 5; ++kk) xf[kk] = *(const bf16x8*)&xr[kk * 32];
    }

    if (t > 0) {
      // wait for all 16 wgs of the group to have published h for step t
      unsigned* cp = mycnt + (t - 1);
      for (;;) {
        unsigned v = 0xFFFFFFFFu;
        if (l == 0) v = __hip_atomic_load(cp, __ATOMIC_RELAXED, __HIP_MEMORY_SCOPE_AGENT);
        v = __shfl((int)v, 0);
        if (v >= 16u) break;
        __builtin_amdgcn_s_sleep(1);
      }
      __builtin_amdgcn_fence(__ATOMIC_ACQUIRE, "agent");
      // stage full h (256 x 16 batch) into LDS, transposed to [n][k=hid]
      const int xtp = dir ? (xt + 1) : (xt - 1);
      const unsigned* hsrc = (const unsigned*)(hseq + (size_t)(dir * T_ + xtp) * H_ * B_ + btile * 16);
      for (int i = tid; i < 2048; i += 256) {
        int hr = i >> 3, p = i & 7;
        unsigned vv = hsrc[hr * 32 + p];
        h_su[(p * 2 + 0) * 264 + hr] = (unsigned short)(vv & 0xFFFFu);
        h_su[(p * 2 + 1) * 264 + hr] = (unsigned short)(vv >> 16);
      }
    }
    __syncthreads();

    if (t > 0) {
      const bf16* Ar = &Whh_s[(wv * 16 + m) * 264 + q * 8];
      const bf16* Br = &h_s[m * 264 + q * 8];
#pragma unroll
      for (int kk = 0; kk < 8; ++kk)
        acc = __builtin_amdgcn_mfma_f32_16x16x32_bf16(*(const bf16x8*)&Ar[kk * 32],
                                                      *(const bf16x8*)&Br[kk * 32], acc, 0, 0, 0);
    }

    // in-lane cell update: reg0=i, reg1=f, reg2=g, reg3=o for (hid, bglob)
    float pi = acc[0], pf = acc[1], pg = acc[2], po = acc[3];
    float ig = 1.f / (1.f + __expf(-pi));
    float fg = 1.f / (1.f + __expf(-pf));
    float og = 1.f / (1.f + __expf(-po));
    float gcl = fminf(fmaxf(pg, -15.f), 15.f);
    float e2 = __expf(2.f * gcl);
    float gg = (e2 - 1.f) / (e2 + 1.f);
    c = fg * c + ig * gg;
    float ccl = fminf(fmaxf(c, -15.f), 15.f);
    float ec = __expf(2.f * ccl);
    float hv = og * ((ec - 1.f) / (ec + 1.f));

    hseq[(size_t)(dir * T_ + xt) * H_ * B_ + (size_t)hid * B_ + bglob] = (bf16)hv;
    __syncthreads();   // drains vmcnt for all waves before the release
    if (tid == 0) {
      __builtin_amdgcn_fence(__ATOMIC_RELEASE, "agent");
      __hip_atomic_fetch_add(mycnt + t, 1u, __ATOMIC_RELAXED, __HIP_MEMORY_SCOPE_AGENT);
    }
  }
}

// ---------------- FC epilogue ----------------
// block = 320 threads: wave o (0..4) computes output column o for all 64 b; one block per t.
__global__ __launch_bounds__(320) void k_fc(const bf16* __restrict__ hseq,
                                            const float* __restrict__ fcw,
                                            const float* __restrict__ fcb,
                                            float* __restrict__ out)
{
  __shared__ float wsm[5 * 512];
  __shared__ bf16  hsm[64 * 64];
  const int tid = threadIdx.x;
  for (int i = tid; i < 2560; i += 320) wsm[i] = fcw[i];
  const int o = tid >> 6, b = tid & 63;
  const int t = blockIdx.x;
  float acc = 0.f;
  for (int ch = 0; ch < 8; ++ch) {
    const int dirc = ch >> 2, hb = (ch & 3) << 6;
    __syncthreads();
    for (int i = tid; i < 2048; i += 320) {
      int hr = i >> 5, dwp = i & 31;
      ((unsigned*)hsm)[hr * 32 + dwp] =
          ((const unsigned*)hseq)[(size_t)((dirc * T_ + t) * H_ + hb + hr) * 32 + dwp];
    }
    __syncthreads();
    const float* wrow = &wsm[o * 512 + dirc * H_ + hb];
#pragma unroll 8
    for (int hh = 0; hh < 64; ++hh)
      acc += wrow[hh] * (float)hsm[hh * 64 + b];
  }
  out[(b * T_ + t) * 5 + o] = acc + fcb[o];
}

// ---------------- launcher ----------------
extern "C" void kernel_launch(void* const* d_in, const int* in_sizes, int n_in,
                              void* d_out, int out_size, void* d_ws, size_t ws_size,
                              hipStream_t stream) {
  const float* x    = (const float*)d_in[0];
  const float* wihf = (const float*)d_in[1];
  const float* whhf = (const float*)d_in[2];
  const float* bihf = (const float*)d_in[3];
  const float* bhhf = (const float*)d_in[4];
  const float* wihb = (const float*)d_in[5];
  const float* whhb = (const float*)d_in[6];
  const float* bihb = (const float*)d_in[7];
  const float* bhhb = (const float*)d_in[8];
  const float* fcw  = (const float*)d_in[9];
  const float* fcb  = (const float*)d_in[10];
  float* out = (float*)d_out;

  char* ws = (char*)d_ws;
  bf16*     xp   = (bf16*)(ws + 0);            // 20,971,520 B
  bf16*     whhp = (bf16*)(ws + 20971520);     //  1,048,576 B
  bf16*     wihp = (bf16*)(ws + 22020096);     //    655,360 B
  float*    bsum = (float*)(ws + 22675456);    //      8,192 B
  unsigned* cnt  = (unsigned*)(ws + 22683648); //     32,768 B (zeroed)
  bf16*     hseq = (bf16*)(ws + 22716416);     // 67,108,864 B
  (void)in_sizes; (void)n_in; (void)out_size; (void)ws_size;

  hipMemsetAsync(cnt, 0, 8 * T_ * sizeof(unsigned), stream);
  k_pack_x   <<<4096, 256, 0, stream>>>(x, xp);
  k_pack_whh <<<1024, 256, 0, stream>>>(whhf, whhb, whhp);
  k_pack_wih <<<640,  256, 0, stream>>>(wihf, wihb, wihp);
  k_pack_bias<<<8,    256, 0, stream>>>(bihf, bhhf, bihb, bhhb, bsum);
  k_lstm     <<<128,  256, 0, stream>>>(xp, whhp, wihp, bsum, hseq, cnt);
  k_fc       <<<1024, 320, 0, stream>>>(hseq, fcw, fcb, out);
}

// Round 2
// 3091.046 us; speedup vs baseline: 2.4490x; 2.4490x over previous
//
#include <hip/hip_runtime.h>
#include <hip/hip_bf16.h>
#include <stdint.h>

#define B_    64
#define T_    1024
#define DIN   136
#define DINP  160
#define H_    256
#define G4H   1024

typedef __bf16 bf16;
typedef __bf16 bf16x8 __attribute__((ext_vector_type(8)));
typedef float  floatx4 __attribute__((ext_vector_type(4)));
typedef int    int4v  __attribute__((ext_vector_type(4)));

// ---------------- pack kernels (unchanged from R1, validated) ----------------
__global__ void k_pack_x(const float* __restrict__ x, bf16* __restrict__ xp) {
  const int n = T_ * B_ * DINP;
  for (int i = blockIdx.x * blockDim.x + threadIdx.x; i < n; i += gridDim.x * blockDim.x) {
    int k  = i % DINP;
    int tb = i / DINP;
    int b  = tb % B_;
    int t  = tb / B_;
    float v = 0.f;
    if (k < DIN) v = x[(b * T_ + t) * DIN + k];
    xp[i] = (bf16)v;   // layout [t][b][k], k zero-padded to 160
  }
}

// packed row r = 4*hid + gate  ->  orig row = gate*256 + hid
__global__ void k_pack_whh(const float* __restrict__ wf, const float* __restrict__ wb,
                           bf16* __restrict__ wp) {
  const int n = 2 * G4H * H_;
  for (int i = blockIdx.x * blockDim.x + threadIdx.x; i < n; i += gridDim.x * blockDim.x) {
    int k   = i & (H_ - 1);
    int r   = (i >> 8) & (G4H - 1);
    int dir = i >> 18;
    int orig = ((r & 3) << 8) | (r >> 2);
    const float* w = dir ? wb : wf;
    wp[i] = (bf16)w[orig * H_ + k];
  }
}

__global__ void k_pack_wih(const float* __restrict__ wf, const float* __restrict__ wb,
                           bf16* __restrict__ wp) {
  const int n = 2 * G4H * DINP;
  for (int i = blockIdx.x * blockDim.x + threadIdx.x; i < n; i += gridDim.x * blockDim.x) {
    int k   = i % DINP;
    int r   = (i / DINP) & (G4H - 1);
    int dir = i / (G4H * DINP);
    int orig = ((r & 3) << 8) | (r >> 2);
    const float* w = dir ? wb : wf;
    float v = (k < DIN) ? w[orig * DIN + k] : 0.f;
    wp[i] = (bf16)v;
  }
}

__global__ void k_pack_bias(const float* __restrict__ bihf, const float* __restrict__ bhhf,
                            const float* __restrict__ bihb, const float* __restrict__ bhhb,
                            float* __restrict__ bs) {
  int i = blockIdx.x * blockDim.x + threadIdx.x;
  if (i >= 2 * G4H) return;
  int r = i & (G4H - 1); int dir = i >> 10;
  int orig = ((r & 3) << 8) | (r >> 2);
  bs[i] = dir ? (bihb[orig] + bhhb[orig]) : (bihf[orig] + bhhf[orig]);
}

// ---------------- persistent LSTM: 32 wgs, weights in registers ----------------
// wg = (dir 2) x (btile 4) x (qtr 4). Owns 64 hid (256 gate rows) x 16 batch.
// 256 thr = 4 waves, 1 wave/SIMD (launch_bounds(256,1) -> 512 VGPR budget).
// Wave w owns rows qtr*256 + w*64 .. +63 (16 hid). All Whh/Wih frags in VGPRs.
// Cross-wg h exchange: relaxed agent-scope atomics (sc1, no cache fences).
__global__ __launch_bounds__(256, 1) void k_lstm(
    const bf16* __restrict__ xp, const bf16* __restrict__ whhp,
    const bf16* __restrict__ wihp, const float* __restrict__ bs,
    bf16* __restrict__ hbuf, unsigned* __restrict__ cnt)
{
  __shared__ bf16 h_sm[2 * 16 * 264];          // double-buffered h: [p][n=16][k=256 pad 264]
  unsigned short* h_su = (unsigned short*)h_sm;

  const int tid = threadIdx.x;
  const int w   = tid >> 6;        // wave 0..3
  const int l   = tid & 63;
  const int q   = l >> 4;
  const int m   = l & 15;

  const int wgid  = blockIdx.x;    // 0..31
  const int g     = wgid >> 2;     // dir*4 + btile
  const int qtr   = wgid & 3;
  const int dir   = g >> 2;
  const int btile = g & 3;
  const int rowbase = qtr * 256 + w * 64;   // gate-row base within this dir's 1024 rows

  // ---- load weight fragments into registers (k-chunk slots rotated: slot s <-> kchunk (qtr*2+s)&7) ----
  bf16x8 wf[4][8];      // Whh: 128 VGPRs
  bf16x8 wif[4][5];     // Wih:  80 VGPRs
  floatx4 bias[4];
#pragma unroll
  for (int tl = 0; tl < 4; ++tl) {
    const bf16* wr = whhp + (size_t)(dir * G4H + rowbase + tl * 16 + m) * H_ + q * 8;
#pragma unroll
    for (int s = 0; s < 8; ++s) {
      int kk = (qtr * 2 + s) & 7;
      wf[tl][s] = *(const bf16x8*)(wr + kk * 32);
    }
    const bf16* wr2 = wihp + (size_t)(dir * G4H + rowbase + tl * 16 + m) * DINP + q * 8;
#pragma unroll
    for (int kk = 0; kk < 5; ++kk) wif[tl][kk] = *(const bf16x8*)(wr2 + kk * 32);
    bias[tl] = *(const floatx4*)(bs + dir * G4H + rowbase + tl * 16 + q * 4);
  }

  unsigned* const cptr    = cnt + g * T_;
  unsigned* const hbuf_dw = (unsigned*)hbuf;
  const size_t hb_g = (size_t)g * T_;          // group base (in 16*128-dword pages)

  float cst[4] = {0.f, 0.f, 0.f, 0.f};

  // initial x fragments
  bf16x8 xf[5];
  {
    const int xt0 = dir ? (T_ - 1) : 0;
    const bf16* xr = xp + (size_t)(xt0 * B_ + btile * 16 + m) * DINP + q * 8;
#pragma unroll
    for (int kk = 0; kk < 5; ++kk) xf[kk] = *(const bf16x8*)(xr + kk * 32);
  }

  for (int t = 0; t < T_; ++t) {
    const int xt = dir ? (T_ - 1 - t) : t;
    floatx4 acc[4] = {bias[0], bias[1], bias[2], bias[3]};

    // input projection (independent of h)
#pragma unroll
    for (int kk = 0; kk < 5; ++kk) {
#pragma unroll
      for (int tl = 0; tl < 4; ++tl)
        acc[tl] = __builtin_amdgcn_mfma_f32_16x16x32_bf16(wif[tl][kk], xf[kk], acc[tl], 0, 0, 0);
    }
    // prefetch next step's x
    if (t + 1 < T_) {
      const int xtn = dir ? (T_ - 2 - t) : (t + 1);
      const bf16* xr = xp + (size_t)(xtn * B_ + btile * 16 + m) * DINP + q * 8;
#pragma unroll
      for (int kk = 0; kk < 5; ++kk) xf[kk] = *(const bf16x8*)(xr + kk * 32);
    }

    if (t > 0) {
      const int p = (t - 1) & 1;
      const bf16* hrow = &h_sm[(p * 16 + m) * 264 + q * 8];

      // own-quarter Whh MFMAs (slots 0,1) — local h, no wait needed
#pragma unroll
      for (int s = 0; s < 2; ++s) {
        int kk = (qtr * 2 + s) & 7;
        bf16x8 bfr = *(const bf16x8*)(hrow + kk * 32);
#pragma unroll
        for (int tl = 0; tl < 4; ++tl)
          acc[tl] = __builtin_amdgcn_mfma_f32_16x16x32_bf16(wf[tl][s], bfr, acc[tl], 0, 0, 0);
      }

      // poll: all 16 waves of the group published step t-1
      {
        unsigned v;
        for (;;) {
          unsigned lv = 0;
          if (l == 0) lv = __hip_atomic_load(cptr + (t - 1), __ATOMIC_RELAXED, __HIP_MEMORY_SCOPE_AGENT);
          v = (unsigned)__shfl((int)lv, 0);
          if (v >= 16u) break;
          __builtin_amdgcn_s_sleep(1);
        }
      }
      __atomic_signal_fence(__ATOMIC_SEQ_CST);

      // stage 3 partner quarters (6 KB) via sc1 atomic loads -> LDS
      {
        const int xtp = dir ? (xt + 1) : (xt - 1);
        const size_t base_dw = (hb_g + xtp) * 16 * 128;
        const int mm = tid >> 4, jj = tid & 15;
        unsigned svals[6];
#pragma unroll
        for (int pp = 0; pp < 3; ++pp) {
          int qq = (qtr + 1 + pp) & 3;
          const unsigned* sp = hbuf_dw + base_dw + (size_t)mm * 128 + qq * 32 + jj;
          svals[pp * 2 + 0] = __hip_atomic_load(sp,      __ATOMIC_RELAXED, __HIP_MEMORY_SCOPE_AGENT);
          svals[pp * 2 + 1] = __hip_atomic_load(sp + 16, __ATOMIC_RELAXED, __HIP_MEMORY_SCOPE_AGENT);
        }
#pragma unroll
        for (int pp = 0; pp < 3; ++pp) {
          int qq = (qtr + 1 + pp) & 3;
          unsigned* dst = (unsigned*)&h_su[(p * 16 + mm) * 264 + qq * 64];
          dst[jj]      = svals[pp * 2 + 0];
          dst[jj + 16] = svals[pp * 2 + 1];
        }
      }
      __syncthreads();

      // partner-quarter Whh MFMAs (slots 2..7)
#pragma unroll
      for (int s = 2; s < 8; ++s) {
        int kk = (qtr * 2 + s) & 7;
        bf16x8 bfr = *(const bf16x8*)(hrow + kk * 32);
#pragma unroll
        for (int tl = 0; tl < 4; ++tl)
          acc[tl] = __builtin_amdgcn_mfma_f32_16x16x32_bf16(wf[tl][s], bfr, acc[tl], 0, 0, 0);
      }
    }

    // in-lane cell update: per tile, reg0=i reg1=f reg2=g reg3=o for (hid, batch)
    unsigned short hu[4];
#pragma unroll
    for (int tl = 0; tl < 4; ++tl) {
      float pi = acc[tl][0], pf = acc[tl][1], pg = acc[tl][2], po = acc[tl][3];
      float ig = 1.f / (1.f + __expf(-pi));
      float fg = 1.f / (1.f + __expf(-pf));
      float og = 1.f / (1.f + __expf(-po));
      float gcl = fminf(fmaxf(pg, -15.f), 15.f);
      float e2  = __expf(2.f * gcl);
      float gg  = (e2 - 1.f) / (e2 + 1.f);
      float c   = fg * cst[tl] + ig * gg;
      cst[tl]   = c;
      float ccl = fminf(fmaxf(c, -15.f), 15.f);
      float ec  = __expf(2.f * ccl);
      float hv  = og * ((ec - 1.f) / (ec + 1.f));
      bf16 hb = (bf16)hv;
      hu[tl] = __builtin_bit_cast(unsigned short, hb);
    }

    // publish own 64 hid x 16 batch (2 KB) ASAP: pair lanes q<->q+1, even-q stores dwords
    {
      const size_t obase = ((hb_g + xt) * 16 + m) * 128 + (size_t)(qtr * 32 + w * 8);
#pragma unroll
      for (int tl = 0; tl < 4; ++tl) {
        int ov = __shfl_xor((int)(unsigned)hu[tl], 16);
        if ((q & 1) == 0) {
          unsigned dw = (unsigned)hu[tl] | ((unsigned)ov << 16);
          __hip_atomic_store(hbuf_dw + obase + tl * 2 + (q >> 1), dw,
                             __ATOMIC_RELAXED, __HIP_MEMORY_SCOPE_AGENT);
        }
      }
    }

    // local h into LDS for next step's own-quarter MFMAs
    {
      const int pcur = t & 1;
      const int hidl = qtr * 64 + w * 16 + q;
#pragma unroll
      for (int tl = 0; tl < 4; ++tl)
        h_su[(pcur * 16 + m) * 264 + hidl + tl * 4] = hu[tl];
    }

    // per-wave: drain publish stores (ack at coherence point), then signal
    asm volatile("s_waitcnt vmcnt(0)" ::: "memory");
    __atomic_signal_fence(__ATOMIC_SEQ_CST);
    if (l == 0)
      __hip_atomic_fetch_add(cptr + t, 1u, __ATOMIC_RELAXED, __HIP_MEMORY_SCOPE_AGENT);
    __syncthreads();
  }
}

// ---------------- FC epilogue ----------------
// one block per t; hbuf layout [g=dir*4+btile][xt][m][hid 256] bf16
__global__ __launch_bounds__(512) void k_fc(const bf16* __restrict__ hbuf,
                                            const float* __restrict__ fcw,
                                            const float* __restrict__ fcb,
                                            float* __restrict__ out)
{
  __shared__ float wsm[5 * 512];
  __shared__ unsigned short hl[64 * 258];      // [b][hid 256 pad 258]
  const int tid = threadIdx.x;
  const int t   = blockIdx.x;
  for (int i = tid; i < 2560; i += 512) wsm[i] = fcw[i];
  const int o = tid / 64, b = tid & 63;
  float acc = 0.f;
  for (int dirc = 0; dirc < 2; ++dirc) {
    __syncthreads();
    for (int i = tid; i < 8192; i += 512) {
      int bb = i >> 7, dd = i & 127;
      int gg = dirc * 4 + (bb >> 4), mm = bb & 15;
      ((unsigned*)hl)[bb * 129 + dd] =
          ((const unsigned*)hbuf)[((size_t)(gg * T_ + t) * 16 + mm) * 128 + dd];
    }
    __syncthreads();
    if (tid < 320) {
      const float* wr = &wsm[o * 512 + dirc * 256];
      const unsigned short* hr = &hl[b * 258];
      float a = 0.f;
#pragma unroll 8
      for (int h = 0; h < 256; ++h) {
        unsigned u = ((unsigned)hr[h]) << 16;
        a += wr[h] * __builtin_bit_cast(float, u);
      }
      acc += a;
    }
  }
  if (tid < 320) out[((size_t)b * T_ + t) * 5 + o] = acc + fcb[o];
}

// ---------------- launcher ----------------
extern "C" void kernel_launch(void* const* d_in, const int* in_sizes, int n_in,
                              void* d_out, int out_size, void* d_ws, size_t ws_size,
                              hipStream_t stream) {
  const float* x    = (const float*)d_in[0];
  const float* wihf = (const float*)d_in[1];
  const float* whhf = (const float*)d_in[2];
  const float* bihf = (const float*)d_in[3];
  const float* bhhf = (const float*)d_in[4];
  const float* wihb = (const float*)d_in[5];
  const float* whhb = (const float*)d_in[6];
  const float* bihb = (const float*)d_in[7];
  const float* bhhb = (const float*)d_in[8];
  const float* fcw  = (const float*)d_in[9];
  const float* fcb  = (const float*)d_in[10];
  float* out = (float*)d_out;

  char* ws = (char*)d_ws;
  bf16*     xp   = (bf16*)(ws + 0);            // 20,971,520 B
  bf16*     whhp = (bf16*)(ws + 20971520);     //  1,048,576 B
  bf16*     wihp = (bf16*)(ws + 22020096);     //    655,360 B
  float*    bsum = (float*)(ws + 22675456);    //      8,192 B
  unsigned* cnt  = (unsigned*)(ws + 22683648); //     32,768 B (zeroed each launch)
  bf16*     hseq = (bf16*)(ws + 22716416);     // 67,108,864 B  [g][xt][m][hid]
  (void)in_sizes; (void)n_in; (void)out_size; (void)ws_size;

  hipMemsetAsync(cnt, 0, 8 * T_ * sizeof(unsigned), stream);
  k_pack_x   <<<4096, 256, 0, stream>>>(x, xp);
  k_pack_whh <<<1024, 256, 0, stream>>>(whhf, whhb, whhp);
  k_pack_wih <<<640,  256, 0, stream>>>(wihf, wihb, wihp);
  k_pack_bias<<<8,    256, 0, stream>>>(bihf, bhhf, bihb, bhhb, bsum);
  k_lstm     <<<32,   256, 0, stream>>>(xp, whhp, wihp, bsum, hseq, cnt);
  k_fc       <<<1024, 512, 0, stream>>>(hseq, fcw, fcb, out);
}